// Round 1
// baseline (270.752 us; speedup 1.0000x reference)
//
#include <hip/hip_runtime.h>

#define B_ 4
#define S_ 2048
#define E_ 1024
#define H_ 16
#define D_ 64
#define BH_ (B_*H_)
#define SD_ (S_*D_)

// log2(e)/8 : folds both 1/sqrt(D) and the exp->exp2 conversion into Q
#define QSCALE 0.18033688011112042f

typedef __attribute__((ext_vector_type(4))) float f32x4;
typedef __attribute__((ext_vector_type(8))) short bf16x8;

#define MFMA(a,b,c) __builtin_amdgcn_mfma_f32_16x16x32_bf16((a),(b),(c),0,0,0)

__device__ __forceinline__ unsigned short f2bf(float f) {
    unsigned int u = __float_as_uint(f);
    unsigned int r = (u + 0x7fffu + ((u >> 16) & 1u)) >> 16;   // RNE
    return (unsigned short)r;
}
__device__ __forceinline__ unsigned int pack2(float a, float b) {
    return (unsigned int)f2bf(a) | ((unsigned int)f2bf(b) << 16);
}

// ---------------------------------------------------------------------------
// prep: W[h][d][e] fp32 -> Wt[mat][h][e][d] bf16 (Q pre-scaled), bias fp32
// ---------------------------------------------------------------------------
__global__ __launch_bounds__(256) void prep_kernel(
    const float* __restrict__ Wq, const float* __restrict__ bq,
    const float* __restrict__ Wk, const float* __restrict__ bk,
    const float* __restrict__ Wv, const float* __restrict__ bv,
    unsigned short* __restrict__ wt, float* __restrict__ bias)
{
    const int blk = blockIdx.x;            // 48 = 3 mats * 16 heads
    const int mat = blk >> 4, h = blk & 15;
    const float* W    = (mat == 0) ? Wq : (mat == 1) ? Wk : Wv;
    const float* bsrc = (mat == 0) ? bq : (mat == 1) ? bk : bv;
    const float scale = (mat == 0) ? QSCALE : 1.0f;
    const int tid = threadIdx.x;
#pragma unroll
    for (int i = 0; i < 16; ++i) {
        int idx = tid + i * 256;           // 0..4095
        int d = idx >> 6, e = idx & 63;
        wt[((mat * H_ + h) << 12) + e * 64 + d] = f2bf(W[h * 4096 + d * 64 + e] * scale);
    }
    if (tid < 64) bias[(mat * H_ + h) * 64 + tid] = bsrc[h * 64 + tid] * scale;
}

// ---------------------------------------------------------------------------
// proj: Q,K -> [bh][s][d] bf16 ; V -> TRANSPOSED [bh][d][s] bf16
// ---------------------------------------------------------------------------
__global__ __launch_bounds__(256) void proj_kernel(
    const float* __restrict__ x,
    const unsigned short* __restrict__ wt,
    const float* __restrict__ bias,
    unsigned short* __restrict__ Qg,
    unsigned short* __restrict__ Kg,
    unsigned short* __restrict__ Vtg)
{
    __shared__ unsigned short x_lds[64 * 64];      // 8 KiB, swizzled 16B slots
    __shared__ unsigned short w_lds[3][64 * 64];   // 24 KiB

    const int blk = blockIdx.x;                    // 2048
    const int bh  = blk >> 5;
    const int s0  = (blk & 31) << 6;
    const int batch = bh >> 4, h = bh & 15;
    const int tid = threadIdx.x, lane = tid & 63, w = tid >> 6;
    const int lo = lane & 15, hi = lane >> 4;

    // stage X tile (64 rows x 64 d) fp32->bf16
#pragma unroll
    for (int rnd = 0; rnd < 4; ++rnd) {
        int c = tid + rnd * 256;                   // 0..1023 chunks of 4 floats
        int row = c >> 4, sl4 = c & 15;
        float4 xv = *(const float4*)(x + (size_t)(batch * S_ + s0 + row) * E_ + h * 64 + sl4 * 4);
        int off = row * 64 + (((sl4 >> 1) ^ (row & 7)) << 3) + ((sl4 & 1) << 2);
        unsigned long long pk4 = (unsigned long long)f2bf(xv.x)
                               | ((unsigned long long)f2bf(xv.y) << 16)
                               | ((unsigned long long)f2bf(xv.z) << 32)
                               | ((unsigned long long)f2bf(xv.w) << 48);
        *(unsigned long long*)(x_lds + off) = pk4;
    }
    // stage Wt (3 x 64e x 64d bf16)
#pragma unroll
    for (int rnd = 0; rnd < 6; ++rnd) {
        int c = tid + rnd * 256;                   // 0..1535 chunks of 16B
        int mat = c >> 9, cc = c & 511;
        int row = cc >> 3, slot = cc & 7;
        *(uint4*)(w_lds[mat] + row * 64 + ((slot ^ (row & 7)) << 3)) =
            *(const uint4*)(wt + ((mat * H_ + h) << 12) + row * 64 + slot * 8);
    }
    __syncthreads();

    const int arow = w * 16 + lo;
    bf16x8 xa0 = *(const bf16x8*)(x_lds + arow * 64 + ((hi ^ (arow & 7)) << 3));
    bf16x8 xa1 = *(const bf16x8*)(x_lds + arow * 64 + (((4 + hi) ^ (arow & 7)) << 3));

    // Q and K : C[q][e] = X . Wt^T
#pragma unroll
    for (int mat = 0; mat < 2; ++mat) {
        unsigned short* Og = mat ? Kg : Qg;
        const unsigned short* wl = w_lds[mat];
#pragma unroll
        for (int et = 0; et < 4; ++et) {
            int erow = et * 16 + lo;
            bf16x8 wb0 = *(const bf16x8*)(wl + erow * 64 + ((hi ^ (erow & 7)) << 3));
            bf16x8 wb1 = *(const bf16x8*)(wl + erow * 64 + (((4 + hi) ^ (erow & 7)) << 3));
            f32x4 acc = {0.f, 0.f, 0.f, 0.f};
            acc = MFMA(xa0, wb0, acc);
            acc = MFMA(xa1, wb1, acc);
            float bb = bias[(mat * H_ + h) * 64 + et * 16 + lo];
#pragma unroll
            for (int r = 0; r < 4; ++r) {
                int srow = s0 + w * 16 + hi * 4 + r;
                Og[bh * SD_ + srow * 64 + et * 16 + lo] = f2bf(acc[r] + bb);
            }
        }
    }
    // V transposed: C[e][s] = Wt_v . X^T  -> store Vt[d=e][s]
    bf16x8 wa0 = *(const bf16x8*)(w_lds[2] + arow * 64 + ((hi ^ (arow & 7)) << 3));
    bf16x8 wa1 = *(const bf16x8*)(w_lds[2] + arow * 64 + (((4 + hi) ^ (arow & 7)) << 3));
    float bvr[4];
#pragma unroll
    for (int r = 0; r < 4; ++r) bvr[r] = bias[(2 * H_ + h) * 64 + w * 16 + hi * 4 + r];
#pragma unroll
    for (int st = 0; st < 4; ++st) {
        int xrow = st * 16 + lo;
        bf16x8 xb0 = *(const bf16x8*)(x_lds + xrow * 64 + ((hi ^ (xrow & 7)) << 3));
        bf16x8 xb1 = *(const bf16x8*)(x_lds + xrow * 64 + (((4 + hi) ^ (xrow & 7)) << 3));
        f32x4 acc = {0.f, 0.f, 0.f, 0.f};
        acc = MFMA(wa0, xb0, acc);
        acc = MFMA(wa1, xb1, acc);
#pragma unroll
        for (int r = 0; r < 4; ++r) {
            int erow = w * 16 + hi * 4 + r;
            Vtg[bh * SD_ + erow * S_ + s0 + st * 16 + lo] = f2bf(acc[r] + bvr[r]);
        }
    }
}

// ---------------------------------------------------------------------------
// attn: flash attention, swapped QK^T, KVBLK=64, 4 waves x 16 q-rows
// ---------------------------------------------------------------------------
__global__ __launch_bounds__(256) void attn_kernel(
    const unsigned short* __restrict__ Qg,
    const unsigned short* __restrict__ Kg,
    const unsigned short* __restrict__ Vtg,
    float* __restrict__ outp)
{
    __shared__ unsigned short k_lds[64 * 64];   // K[k][d]  swizzled
    __shared__ unsigned short v_lds[64 * 64];   // Vt[d][k] swizzled

    const int blk = blockIdx.x;                 // 2048, XCD-bijective swizzle
    const int bh  = (blk & 7) + ((blk >> 8) << 3);
    const int qt  = (blk >> 3) & 31;
    const int batch = bh >> 4, h = bh & 15;
    const int tid = threadIdx.x, lane = tid & 63, w = tid >> 6;
    const int lo = lane & 15, hi = lane >> 4;
    const int q0 = qt * 64 + w * 16;

    const unsigned short* Qb = Qg  + bh * SD_;
    const unsigned short* Kb = Kg  + bh * SD_;
    const unsigned short* Vb = Vtg + bh * SD_;

    // Q B-frags (scaled at projection): lane holds Q[q0+lo][dk*32 + hi*8 .. +8]
    bf16x8 qf0 = *(const bf16x8*)(Qb + (q0 + lo) * 64 + hi * 8);
    bf16x8 qf1 = *(const bf16x8*)(Qb + (q0 + lo) * 64 + 32 + hi * 8);

    // staging chunks: two 16B chunks per thread per buffer
    const int crow = tid >> 3, cslot = tid & 7;
    const int ldsoff = crow * 64 + ((cslot ^ (crow & 7)) << 3);        // rows 0..31
    const int ldsoff2 = (crow + 32) * 64 + ((cslot ^ (crow & 7)) << 3); // rows 32..63

    f32x4 o[4];
#pragma unroll
    for (int dt = 0; dt < 4; ++dt) o[dt] = (f32x4){0.f, 0.f, 0.f, 0.f};
    float m_run = -1e30f, l_run = 0.0f;

    for (int kt0 = 0; kt0 < S_; kt0 += 64) {
        __syncthreads();
        *(uint4*)(k_lds + ldsoff)  = *(const uint4*)(Kb + (kt0 + crow) * 64 + cslot * 8);
        *(uint4*)(k_lds + ldsoff2) = *(const uint4*)(Kb + (kt0 + crow + 32) * 64 + cslot * 8);
        *(uint4*)(v_lds + ldsoff)  = *(const uint4*)(Vb + crow * S_ + kt0 + cslot * 8);
        *(uint4*)(v_lds + ldsoff2) = *(const uint4*)(Vb + (crow + 32) * S_ + kt0 + cslot * 8);
        __syncthreads();

        // S^T[k][q] = K . Q^T  (4 k-subtiles of 16)
        f32x4 st[4];
#pragma unroll
        for (int kt = 0; kt < 4; ++kt) {
            int row = kt * 16 + lo;
            bf16x8 ka0 = *(const bf16x8*)(k_lds + row * 64 + ((hi ^ (row & 7)) << 3));
            bf16x8 ka1 = *(const bf16x8*)(k_lds + row * 64 + (((4 + hi) ^ (row & 7)) << 3));
            f32x4 acc = {0.f, 0.f, 0.f, 0.f};
            acc = MFMA(ka0, qf0, acc);
            acc = MFMA(ka1, qf1, acc);
            st[kt] = acc;
        }

        // online softmax (exp2 domain; scale pre-folded into Q)
        float mx = st[0][0];
#pragma unroll
        for (int kt = 0; kt < 4; ++kt)
#pragma unroll
            for (int r = 0; r < 4; ++r) mx = fmaxf(mx, st[kt][r]);
        mx = fmaxf(mx, __shfl_xor(mx, 16));
        mx = fmaxf(mx, __shfl_xor(mx, 32));
        float m_new = fmaxf(m_run, mx);
        float alpha = exp2f(m_run - m_new);
        float p[4][4];
        float rs = 0.f;
#pragma unroll
        for (int kt = 0; kt < 4; ++kt)
#pragma unroll
            for (int r = 0; r < 4; ++r) {
                float e = exp2f(st[kt][r] - m_new);
                p[kt][r] = e;
                rs += e;
            }
        rs += __shfl_xor(rs, 16);
        rs += __shfl_xor(rs, 32);
        l_run = l_run * alpha + rs;
        m_run = m_new;
#pragma unroll
        for (int dt = 0; dt < 4; ++dt) o[dt] *= alpha;

        // P^T (C-layout) -> B-frags via register shuffles
        unsigned int pk[4][2];
#pragma unroll
        for (int kt = 0; kt < 4; ++kt) {
            pk[kt][0] = pack2(p[kt][0], p[kt][1]);
            pk[kt][1] = pack2(p[kt][2], p[kt][3]);
        }
        union Frag { bf16x8 v; unsigned int u[4]; };
        Frag pb0, pb1;
#pragma unroll
        for (int pp = 0; pp < 4; ++pp) {
            int srcl = lo + ((((hi & 1) << 1) + (pp >> 1)) << 4);
            unsigned int a0 = (unsigned int)__shfl((int)pk[0][pp & 1], srcl);
            unsigned int b0 = (unsigned int)__shfl((int)pk[1][pp & 1], srcl);
            pb0.u[pp] = (hi >= 2) ? b0 : a0;
            unsigned int a1 = (unsigned int)__shfl((int)pk[2][pp & 1], srcl);
            unsigned int b1 = (unsigned int)__shfl((int)pk[3][pp & 1], srcl);
            pb1.u[pp] = (hi >= 2) ? b1 : a1;
        }

        // O^T[d][q] += V^T . P^T
#pragma unroll
        for (int dt = 0; dt < 4; ++dt) {
            int row = dt * 16 + lo;
            bf16x8 va0 = *(const bf16x8*)(v_lds + row * 64 + ((hi ^ (row & 7)) << 3));
            bf16x8 va1 = *(const bf16x8*)(v_lds + row * 64 + (((4 + hi) ^ (row & 7)) << 3));
            o[dt] = MFMA(va0, pb0.v, o[dt]);
            o[dt] = MFMA(va1, pb1.v, o[dt]);
        }
    }

    const float inv = 1.0f / l_run;
    const int s = q0 + lo;
    float* ob = outp + (size_t)(batch * S_ + s) * E_ + h * 64;
#pragma unroll
    for (int dt = 0; dt < 4; ++dt)
#pragma unroll
        for (int r = 0; r < 4; ++r)
            ob[dt * 16 + hi * 4 + r] = o[dt][r] * inv;
}

// ---------------------------------------------------------------------------
extern "C" void kernel_launch(void* const* d_in, const int* in_sizes, int n_in,
                              void* d_out, int out_size, void* d_ws, size_t ws_size,
                              hipStream_t stream)
{
    const float* x  = (const float*)d_in[0];
    const float* Wq = (const float*)d_in[1];
    const float* bq = (const float*)d_in[2];
    const float* Wk = (const float*)d_in[3];
    const float* bk = (const float*)d_in[4];
    const float* Wv = (const float*)d_in[5];
    const float* bv = (const float*)d_in[6];

    char* ws = (char*)d_ws;
    unsigned short* wt   = (unsigned short*)ws;                       // 393216 B
    float*          bias = (float*)(ws + 393216);                     // 12288 B
    unsigned short* Qg   = (unsigned short*)(ws + 405504);            // 16 MiB
    unsigned short* Kg   = (unsigned short*)(ws + 405504 + 16777216);
    unsigned short* Vtg  = (unsigned short*)(ws + 405504 + 2 * 16777216);
    float* outp = (float*)d_out;

    hipLaunchKernelGGL(prep_kernel, dim3(48),   dim3(256), 0, stream,
                       Wq, bq, Wk, bk, Wv, bv, wt, bias);
    hipLaunchKernelGGL(proj_kernel, dim3(2048), dim3(256), 0, stream,
                       x, wt, bias, Qg, Kg, Vtg);
    hipLaunchKernelGGL(attn_kernel, dim3(2048), dim3(256), 0, stream,
                       Qg, Kg, Vtg, outp);
}

// Round 3
// 226.174 us; speedup vs baseline: 1.1971x; 1.1971x over previous
//
#include <hip/hip_runtime.h>

#define B_ 4
#define S_ 2048
#define E_ 1024
#define H_ 16
#define D_ 64
#define BH_ (B_*H_)
#define SD_ (S_*D_)

// log2(e)/8 : folds both 1/sqrt(D) and the exp->exp2 conversion into Q
#define QSCALE 0.18033688011112042f

typedef __attribute__((ext_vector_type(4))) float f32x4;
typedef __attribute__((ext_vector_type(8))) short bf16x8;
typedef __attribute__((ext_vector_type(2))) unsigned int uint2v;

#define MFMA(a,b,c) __builtin_amdgcn_mfma_f32_16x16x32_bf16((a),(b),(c),0,0,0)

__device__ __forceinline__ unsigned short f2bf(float f) {
    unsigned int u = __float_as_uint(f);
    unsigned int r = (u + 0x7fffu + ((u >> 16) & 1u)) >> 16;   // RNE
    return (unsigned short)r;
}

// v_cvt_pk_bf16_f32: dst.lo = bf16(a), dst.hi = bf16(b) (RNE)
__device__ __forceinline__ unsigned int cvtpk(float a, float b) {
    unsigned int r;
    asm("v_cvt_pk_bf16_f32 %0, %1, %2" : "=v"(r) : "v"(a), "v"(b));
    return r;
}

// v_exp_f32: r = 2^x (hardware transcendental)
__device__ __forceinline__ float exp2fast(float x) {
    float r;
    asm("v_exp_f32 %0, %1" : "=v"(r) : "v"(x));
    return r;
}

// ---------------------------------------------------------------------------
// prep: W[h][d][e] fp32 -> Wt[mat][h][e][d] bf16 (Q pre-scaled), bias fp32
// ---------------------------------------------------------------------------
__global__ __launch_bounds__(256) void prep_kernel(
    const float* __restrict__ Wq, const float* __restrict__ bq,
    const float* __restrict__ Wk, const float* __restrict__ bk,
    const float* __restrict__ Wv, const float* __restrict__ bv,
    unsigned short* __restrict__ wt, float* __restrict__ bias)
{
    const int blk = blockIdx.x;            // 48 = 3 mats * 16 heads
    const int mat = blk >> 4, h = blk & 15;
    const float* W    = (mat == 0) ? Wq : (mat == 1) ? Wk : Wv;
    const float* bsrc = (mat == 0) ? bq : (mat == 1) ? bk : bv;
    const float scale = (mat == 0) ? QSCALE : 1.0f;
    const int tid = threadIdx.x;
#pragma unroll
    for (int i = 0; i < 16; ++i) {
        int idx = tid + i * 256;           // 0..4095
        int d = idx >> 6, e = idx & 63;
        wt[((mat * H_ + h) << 12) + e * 64 + d] = f2bf(W[h * 4096 + d * 64 + e] * scale);
    }
    if (tid < 64) bias[(mat * H_ + h) * 64 + tid] = bsrc[h * 64 + tid] * scale;
}

// ---------------------------------------------------------------------------
// proj: Q,K -> [bh][s][d] bf16 ; V -> TRANSPOSED [bh][d][s] bf16
// Transposed-C MFMA so every thread's 4 C-values are memory-contiguous.
// ---------------------------------------------------------------------------
__global__ __launch_bounds__(256) void proj_kernel(
    const float* __restrict__ x,
    const unsigned short* __restrict__ wt,
    const float* __restrict__ bias,
    unsigned short* __restrict__ Qg,
    unsigned short* __restrict__ Kg,
    unsigned short* __restrict__ Vtg)
{
    __shared__ unsigned short x_lds[64 * 64];      // 8 KiB, swizzled 16B slots
    __shared__ unsigned short w_lds[3][64 * 64];   // 24 KiB

    const int blk = blockIdx.x;                    // 2048
    const int bh  = blk >> 5;
    const int s0  = (blk & 31) << 6;
    const int batch = bh >> 4, h = bh & 15;
    const int tid = threadIdx.x, lane = tid & 63, w = tid >> 6;
    const int lo = lane & 15, hi = lane >> 4;

    // stage X tile (64 s-rows x 64 d) fp32->bf16, swizzled
#pragma unroll
    for (int rnd = 0; rnd < 4; ++rnd) {
        int c = tid + rnd * 256;                   // 0..1023 chunks of 4 floats
        int row = c >> 4, sl4 = c & 15;
        float4 xv = *(const float4*)(x + (size_t)(batch * S_ + s0 + row) * E_ + h * 64 + sl4 * 4);
        int off = row * 64 + (((sl4 >> 1) ^ (row & 7)) << 3) + ((sl4 & 1) << 2);
        uint2 pk;
        pk.x = cvtpk(xv.x, xv.y);
        pk.y = cvtpk(xv.z, xv.w);
        *(uint2*)(x_lds + off) = pk;
    }
    // stage Wt (3 x 64e x 64d bf16), swizzled
#pragma unroll
    for (int rnd = 0; rnd < 6; ++rnd) {
        int c = tid + rnd * 256;                   // 0..1535 chunks of 16B
        int mat = c >> 9, cc = c & 511;
        int row = cc >> 3, slot = cc & 7;
        *(uint4*)(w_lds[mat] + row * 64 + ((slot ^ (row & 7)) << 3)) =
            *(const uint4*)(wt + ((mat * H_ + h) << 12) + row * 64 + slot * 8);
    }
    __syncthreads();

    // this wave's s-chunk x fragments (shared by Q/K B-operand and V A-operand)
    const int xrow = w * 16 + lo;
    bf16x8 xf0 = *(const bf16x8*)(x_lds + xrow * 64 + ((hi ^ (xrow & 7)) << 3));
    bf16x8 xf1 = *(const bf16x8*)(x_lds + xrow * 64 + (((4 + hi) ^ (xrow & 7)) << 3));

    // Q, K: C[e][s] = Wt . X^T  -> thread holds e = et*16+hi*4+(0..3), s = w*16+lo
#pragma unroll
    for (int mat = 0; mat < 2; ++mat) {
        unsigned short* Og = mat ? Kg : Qg;
        const unsigned short* wl = w_lds[mat];
        unsigned short* orow = Og + bh * SD_ + (s0 + w * 16 + lo) * 64;
#pragma unroll
        for (int et = 0; et < 4; ++et) {
            int erow = et * 16 + lo;
            bf16x8 wa0 = *(const bf16x8*)(wl + erow * 64 + ((hi ^ (erow & 7)) << 3));
            bf16x8 wa1 = *(const bf16x8*)(wl + erow * 64 + (((4 + hi) ^ (erow & 7)) << 3));
            f32x4 acc = {0.f, 0.f, 0.f, 0.f};
            acc = MFMA(wa0, xf0, acc);
            acc = MFMA(wa1, xf1, acc);
            f32x4 bv = *(const f32x4*)(bias + (mat * H_ + h) * 64 + et * 16 + hi * 4);
            acc += bv;
            uint2 pk;
            pk.x = cvtpk(acc[0], acc[1]);
            pk.y = cvtpk(acc[2], acc[3]);
            *(uint2*)(orow + et * 16 + hi * 4) = pk;
        }
    }
    // V: C[s][e] = X . Wv  -> thread holds s = w*16+hi*4+(0..3), e = nt*16+lo
    // stored as Vt[d=e][s]: the 4 values are s-contiguous -> packed 8B store
#pragma unroll
    for (int nt = 0; nt < 4; ++nt) {
        int erow = nt * 16 + lo;
        bf16x8 wb0 = *(const bf16x8*)(w_lds[2] + erow * 64 + ((hi ^ (erow & 7)) << 3));
        bf16x8 wb1 = *(const bf16x8*)(w_lds[2] + erow * 64 + (((4 + hi) ^ (erow & 7)) << 3));
        f32x4 acc = {0.f, 0.f, 0.f, 0.f};
        acc = MFMA(xf0, wb0, acc);
        acc = MFMA(xf1, wb1, acc);
        float bvv = bias[(2 * H_ + h) * 64 + nt * 16 + lo];
        acc += bvv;
        uint2 pk;
        pk.x = cvtpk(acc[0], acc[1]);
        pk.y = cvtpk(acc[2], acc[3]);
        *(uint2*)(Vtg + bh * SD_ + erow * S_ + s0 + w * 16 + hi * 4) = pk;
    }
}

// ---------------------------------------------------------------------------
// attn: flash attention, swapped QK^T, KVBLK=64, 4 waves x 16 q-rows
// reg-staged async prefetch + LDS double buffer, 1 barrier/tile
// ---------------------------------------------------------------------------
__global__ __launch_bounds__(256) void attn_kernel(
    const unsigned short* __restrict__ Qg,
    const unsigned short* __restrict__ Kg,
    const unsigned short* __restrict__ Vtg,
    float* __restrict__ outp)
{
    __shared__ unsigned short k_lds[2][64 * 64];   // K[k][d]  swizzled
    __shared__ unsigned short v_lds[2][64 * 64];   // Vt[d][k] swizzled

    const int blk = blockIdx.x;                 // 2048, XCD-bijective swizzle
    const int bh  = (blk & 7) + ((blk >> 8) << 3);
    const int qt  = (blk >> 3) & 31;
    const int batch = bh >> 4, h = bh & 15;
    const int tid = threadIdx.x, lane = tid & 63, w = tid >> 6;
    const int lo = lane & 15, hi = lane >> 4;
    const int q0 = qt * 64 + w * 16;

    const unsigned short* Qb = Qg  + bh * SD_;
    const unsigned short* Kb = Kg  + bh * SD_;
    const unsigned short* Vb = Vtg + bh * SD_;

    // Q B-frags (scale pre-folded): lane holds Q[q0+lo][hi*8..+8], [32+hi*8..+8]
    bf16x8 qf0 = *(const bf16x8*)(Qb + (q0 + lo) * 64 + hi * 8);
    bf16x8 qf1 = *(const bf16x8*)(Qb + (q0 + lo) * 64 + 32 + hi * 8);

    // staging: each thread moves two 16B chunks per buffer
    const int crow = tid >> 3, cslot = tid & 7;
    const int swz  = (cslot ^ (crow & 7)) << 3;
    const int ldsA = crow * 64 + swz;
    const int ldsB = (crow + 32) * 64 + swz;
    const unsigned short* kp0 = Kb + crow * 64 + cslot * 8;
    const unsigned short* kp1 = Kb + (crow + 32) * 64 + cslot * 8;
    const unsigned short* vp0 = Vb + crow * S_ + cslot * 8;
    const unsigned short* vp1 = Vb + (crow + 32) * S_ + cslot * 8;

    f32x4 o[4];
#pragma unroll
    for (int dt = 0; dt < 4; ++dt) o[dt] = (f32x4){0.f, 0.f, 0.f, 0.f};
    float m_run = -1e30f, l_run = 0.0f;

    // prologue: tile 0 into reg set R
    uint4 rk0 = *(const uint4*)(kp0);
    uint4 rk1 = *(const uint4*)(kp1);
    uint4 rv0 = *(const uint4*)(vp0);
    uint4 rv1 = *(const uint4*)(vp1);
    uint4 sk0, sk1, sv0, sv1;

    auto compute = [&](const unsigned short* kl, const unsigned short* vl) {
        // S^T[k][q] = K . Q^T
        f32x4 st[4];
        __builtin_amdgcn_s_setprio(1);
#pragma unroll
        for (int kt = 0; kt < 4; ++kt) {
            int row = kt * 16 + lo;
            bf16x8 ka0 = *(const bf16x8*)(kl + row * 64 + ((hi ^ (row & 7)) << 3));
            bf16x8 ka1 = *(const bf16x8*)(kl + row * 64 + (((4 + hi) ^ (row & 7)) << 3));
            f32x4 acc = {0.f, 0.f, 0.f, 0.f};
            acc = MFMA(ka0, qf0, acc);
            acc = MFMA(ka1, qf1, acc);
            st[kt] = acc;
        }
        __builtin_amdgcn_s_setprio(0);

        // row max across this thread's 16 k-values, then across hi groups
        float m0 = fmaxf(fmaxf(st[0][0], st[0][1]), fmaxf(st[0][2], st[0][3]));
        float m1 = fmaxf(fmaxf(st[1][0], st[1][1]), fmaxf(st[1][2], st[1][3]));
        float m2 = fmaxf(fmaxf(st[2][0], st[2][1]), fmaxf(st[2][2], st[2][3]));
        float m3 = fmaxf(fmaxf(st[3][0], st[3][1]), fmaxf(st[3][2], st[3][3]));
        float mx = fmaxf(fmaxf(m0, m1), fmaxf(m2, m3));
        mx = fmaxf(mx, __shfl_xor(mx, 16));
        mx = fmaxf(mx, __shfl_xor(mx, 32));

        // defer-max (T13): only rescale when the max grew by > 8 (exp2 domain)
        if (!__all(mx - m_run <= 8.0f)) {
            float m_new = fmaxf(m_run, mx);
            float alpha = exp2fast(m_run - m_new);
            l_run *= alpha;
#pragma unroll
            for (int dt = 0; dt < 4; ++dt) o[dt] *= alpha;
            m_run = m_new;
        }

        // P = exp2(S - m_run), packed straight to bf16 pairs
        float rs = 0.f;
        unsigned int pk[4][2];
#pragma unroll
        for (int kt = 0; kt < 4; ++kt) {
            float e0 = exp2fast(st[kt][0] - m_run);
            float e1 = exp2fast(st[kt][1] - m_run);
            float e2 = exp2fast(st[kt][2] - m_run);
            float e3 = exp2fast(st[kt][3] - m_run);
            rs += (e0 + e1) + (e2 + e3);
            pk[kt][0] = cvtpk(e0, e1);
            pk[kt][1] = cvtpk(e2, e3);
        }
        rs += __shfl_xor(rs, 16);
        rs += __shfl_xor(rs, 32);
        l_run += rs;

        // P^T C-layout -> B-frags: permlane32_swap + ds_swizzle(xor16) + select
        union Frag { bf16x8 v; unsigned int u[4]; };
        Frag pb0, pb1;
        const bool oddhi = (hi & 1);
#pragma unroll
        for (int c = 0; c < 2; ++c) {
            uint2v r = __builtin_amdgcn_permlane32_swap(pk[0][c], pk[1][c], false, false);
            unsigned int sx = (unsigned int)__builtin_amdgcn_ds_swizzle((int)r.x, 0x401F);
            unsigned int sy = (unsigned int)__builtin_amdgcn_ds_swizzle((int)r.y, 0x401F);
            pb0.u[c]     = oddhi ? sy  : r.x;
            pb0.u[2 + c] = oddhi ? r.y : sx;
            uint2v r2 = __builtin_amdgcn_permlane32_swap(pk[2][c], pk[3][c], false, false);
            unsigned int sx2 = (unsigned int)__builtin_amdgcn_ds_swizzle((int)r2.x, 0x401F);
            unsigned int sy2 = (unsigned int)__builtin_amdgcn_ds_swizzle((int)r2.y, 0x401F);
            pb1.u[c]     = oddhi ? sy2  : r2.x;
            pb1.u[2 + c] = oddhi ? r2.y : sx2;
        }

        // O^T[d][q] += V^T . P^T
        __builtin_amdgcn_s_setprio(1);
#pragma unroll
        for (int dt = 0; dt < 4; ++dt) {
            int row = dt * 16 + lo;
            bf16x8 va0 = *(const bf16x8*)(vl + row * 64 + ((hi ^ (row & 7)) << 3));
            bf16x8 va1 = *(const bf16x8*)(vl + row * 64 + (((4 + hi) ^ (row & 7)) << 3));
            o[dt] = MFMA(va0, pb0.v, o[dt]);
            o[dt] = MFMA(va1, pb1.v, o[dt]);
        }
        __builtin_amdgcn_s_setprio(0);
    };

#pragma unroll 1
    for (int t = 0; t < 32; t += 2) {
        // half A: write R -> buf0, prefetch tile t+1 -> S, compute buf0
        *(uint4*)(k_lds[0] + ldsA) = rk0;
        *(uint4*)(k_lds[0] + ldsB) = rk1;
        *(uint4*)(v_lds[0] + ldsA) = rv0;
        *(uint4*)(v_lds[0] + ldsB) = rv1;
        {
            int ko = (t + 1) * 4096;               // (t+1)*64 rows * 64 elems
            int vo = (t + 1) * 64;
            sk0 = *(const uint4*)(kp0 + ko);
            sk1 = *(const uint4*)(kp1 + ko);
            sv0 = *(const uint4*)(vp0 + vo);
            sv1 = *(const uint4*)(vp1 + vo);
        }
        __syncthreads();
        compute(k_lds[0], v_lds[0]);

        // half B: write S -> buf1, prefetch tile t+2 -> R, compute buf1
        *(uint4*)(k_lds[1] + ldsA) = sk0;
        *(uint4*)(k_lds[1] + ldsB) = sk1;
        *(uint4*)(v_lds[1] + ldsA) = sv0;
        *(uint4*)(v_lds[1] + ldsB) = sv1;
        if (t + 2 < 32) {
            int ko = (t + 2) * 4096;
            int vo = (t + 2) * 64;
            rk0 = *(const uint4*)(kp0 + ko);
            rk1 = *(const uint4*)(kp1 + ko);
            rv0 = *(const uint4*)(vp0 + vo);
            rv1 = *(const uint4*)(vp1 + vo);
        }
        __syncthreads();
        compute(k_lds[1], v_lds[1]);
    }

    const float inv = 1.0f / l_run;
    float* ob = outp + (size_t)(batch * S_ + q0 + lo) * E_ + h * 64;
#pragma unroll
    for (int dt = 0; dt < 4; ++dt) {
        f32x4 r = o[dt] * inv;
        *(f32x4*)(ob + dt * 16 + hi * 4) = r;     // 16B coalesced store
    }
}

// ---------------------------------------------------------------------------
extern "C" void kernel_launch(void* const* d_in, const int* in_sizes, int n_in,
                              void* d_out, int out_size, void* d_ws, size_t ws_size,
                              hipStream_t stream)
{
    const float* x  = (const float*)d_in[0];
    const float* Wq = (const float*)d_in[1];
    const float* bq = (const float*)d_in[2];
    const float* Wk = (const float*)d_in[3];
    const float* bk = (const float*)d_in[4];
    const float* Wv = (const float*)d_in[5];
    const float* bv = (const float*)d_in[6];

    char* ws = (char*)d_ws;
    unsigned short* wt   = (unsigned short*)ws;                       // 393216 B
    float*          bias = (float*)(ws + 393216);                     // 12288 B
    unsigned short* Qg   = (unsigned short*)(ws + 405504);            // 16 MiB
    unsigned short* Kg   = (unsigned short*)(ws + 405504 + 16777216);
    unsigned short* Vtg  = (unsigned short*)(ws + 405504 + 2 * 16777216);
    float* outp = (float*)d_out;

    hipLaunchKernelGGL(prep_kernel, dim3(48),   dim3(256), 0, stream,
                       Wq, bq, Wk, bk, Wv, bv, wt, bias);
    hipLaunchKernelGGL(proj_kernel, dim3(2048), dim3(256), 0, stream,
                       x, wt, bias, Qg, Kg, Vtg);
    hipLaunchKernelGGL(attn_kernel, dim3(2048), dim3(256), 0, stream,
                       Qg, Kg, Vtg, outp);
}

// Round 4
// 214.072 us; speedup vs baseline: 1.2648x; 1.0565x over previous
//
#include <hip/hip_runtime.h>

#define B_ 4
#define S_ 2048
#define E_ 1024
#define H_ 16
#define D_ 64
#define BH_ (B_*H_)
#define SD_ (S_*D_)

// log2(e)/8 : folds both 1/sqrt(D) and the exp->exp2 conversion into Q
#define QSCALE 0.18033688011112042f

typedef __attribute__((ext_vector_type(4))) float f32x4;
typedef __attribute__((ext_vector_type(8))) short bf16x8;
typedef __attribute__((ext_vector_type(2))) unsigned int uint2v;

#define MFMA(a,b,c) __builtin_amdgcn_mfma_f32_16x16x32_bf16((a),(b),(c),0,0,0)

__device__ __forceinline__ unsigned short f2bf(float f) {
    unsigned int u = __float_as_uint(f);
    unsigned int r = (u + 0x7fffu + ((u >> 16) & 1u)) >> 16;   // RNE
    return (unsigned short)r;
}

// v_cvt_pk_bf16_f32: dst.lo = bf16(a), dst.hi = bf16(b) (RNE)
__device__ __forceinline__ unsigned int cvtpk(float a, float b) {
    unsigned int r;
    asm("v_cvt_pk_bf16_f32 %0, %1, %2" : "=v"(r) : "v"(a), "v"(b));
    return r;
}

// v_exp_f32: r = 2^x (hardware transcendental)
__device__ __forceinline__ float exp2fast(float x) {
    float r;
    asm("v_exp_f32 %0, %1" : "=v"(r) : "v"(x));
    return r;
}

// async global->LDS, 16B per lane; LDS dest = wave-uniform base + lane*16
__device__ __forceinline__ void gload16(const void* g, void* l) {
    __builtin_amdgcn_global_load_lds(
        (const __attribute__((address_space(1))) unsigned int*)g,
        (__attribute__((address_space(3))) unsigned int*)l, 16, 0, 0);
}

// ---------------------------------------------------------------------------
// prep: W[h][d][e] fp32 -> Wt[mat][h][e][d] bf16 (Q pre-scaled), bias fp32
// ---------------------------------------------------------------------------
__global__ __launch_bounds__(256) void prep_kernel(
    const float* __restrict__ Wq, const float* __restrict__ bq,
    const float* __restrict__ Wk, const float* __restrict__ bk,
    const float* __restrict__ Wv, const float* __restrict__ bv,
    unsigned short* __restrict__ wt, float* __restrict__ bias)
{
    const int blk = blockIdx.x;            // 48 = 3 mats * 16 heads
    const int mat = blk >> 4, h = blk & 15;
    const float* W    = (mat == 0) ? Wq : (mat == 1) ? Wk : Wv;
    const float* bsrc = (mat == 0) ? bq : (mat == 1) ? bk : bv;
    const float scale = (mat == 0) ? QSCALE : 1.0f;
    const int tid = threadIdx.x;
#pragma unroll
    for (int i = 0; i < 16; ++i) {
        int idx = tid + i * 256;           // 0..4095
        int d = idx >> 6, e = idx & 63;
        wt[((mat * H_ + h) << 12) + e * 64 + d] = f2bf(W[h * 4096 + d * 64 + e] * scale);
    }
    if (tid < 64) bias[(mat * H_ + h) * 64 + tid] = bsrc[h * 64 + tid] * scale;
}

// ---------------------------------------------------------------------------
// proj: Q -> [bh][s][d] bf16 (row layout);
//       K,V -> TILED+SWIZZLED [bh][t][4096] bf16: 16B-chunk (row*8 + (sl^(row&7)))
//       holds logical slot sl of row  (row = k-local for K, d for Vt).
//       This is exactly the LDS image attn's linear global_load_lds expects.
// ---------------------------------------------------------------------------
__global__ __launch_bounds__(256) void proj_kernel(
    const float* __restrict__ x,
    const unsigned short* __restrict__ wt,
    const float* __restrict__ bias,
    unsigned short* __restrict__ Qg,
    unsigned short* __restrict__ Kg,
    unsigned short* __restrict__ Vtg)
{
    __shared__ unsigned short x_lds[64 * 64];      // 8 KiB, swizzled 16B slots
    __shared__ unsigned short w_lds[3][64 * 64];   // 24 KiB

    const int blk = blockIdx.x;                    // 2048
    const int bh  = blk >> 5;
    const int t_  = blk & 31;                      // s-tile index
    const int s0  = t_ << 6;
    const int batch = bh >> 4, h = bh & 15;
    const int tid = threadIdx.x, lane = tid & 63, w = tid >> 6;
    const int lo = lane & 15, hi = lane >> 4;

    // stage X tile (64 s-rows x 64 d) fp32->bf16, swizzled
#pragma unroll
    for (int rnd = 0; rnd < 4; ++rnd) {
        int c = tid + rnd * 256;                   // 0..1023 chunks of 4 floats
        int row = c >> 4, sl4 = c & 15;
        float4 xv = *(const float4*)(x + (size_t)(batch * S_ + s0 + row) * E_ + h * 64 + sl4 * 4);
        int off = row * 64 + (((sl4 >> 1) ^ (row & 7)) << 3) + ((sl4 & 1) << 2);
        uint2 pk;
        pk.x = cvtpk(xv.x, xv.y);
        pk.y = cvtpk(xv.z, xv.w);
        *(uint2*)(x_lds + off) = pk;
    }
    // stage Wt (3 x 64e x 64d bf16), swizzled
#pragma unroll
    for (int rnd = 0; rnd < 6; ++rnd) {
        int c = tid + rnd * 256;                   // 0..1535 chunks of 16B
        int mat = c >> 9, cc = c & 511;
        int row = cc >> 3, slot = cc & 7;
        *(uint4*)(w_lds[mat] + row * 64 + ((slot ^ (row & 7)) << 3)) =
            *(const uint4*)(wt + ((mat * H_ + h) << 12) + row * 64 + slot * 8);
    }
    __syncthreads();

    // this wave's s-chunk x fragments (shared by Q/K B-operand and V A-operand)
    const int xrow = w * 16 + lo;
    bf16x8 xf0 = *(const bf16x8*)(x_lds + xrow * 64 + ((hi ^ (xrow & 7)) << 3));
    bf16x8 xf1 = *(const bf16x8*)(x_lds + xrow * 64 + (((4 + hi) ^ (xrow & 7)) << 3));

    // Q, K: C[e][s] = Wt . X^T  -> thread holds e = et*16+hi*4+(0..3), s = w*16+lo
#pragma unroll
    for (int mat = 0; mat < 2; ++mat) {
        const unsigned short* wl = w_lds[mat];
#pragma unroll
        for (int et = 0; et < 4; ++et) {
            int erow = et * 16 + lo;
            bf16x8 wa0 = *(const bf16x8*)(wl + erow * 64 + ((hi ^ (erow & 7)) << 3));
            bf16x8 wa1 = *(const bf16x8*)(wl + erow * 64 + (((4 + hi) ^ (erow & 7)) << 3));
            f32x4 acc = {0.f, 0.f, 0.f, 0.f};
            acc = MFMA(wa0, xf0, acc);
            acc = MFMA(wa1, xf1, acc);
            f32x4 bv = *(const f32x4*)(bias + (mat * H_ + h) * 64 + et * 16 + hi * 4);
            acc += bv;
            uint2 pk;
            pk.x = cvtpk(acc[0], acc[1]);
            pk.y = cvtpk(acc[2], acc[3]);
            if (mat == 0) {
                // Q: plain row layout [s][e]
                *(uint2*)(Qg + bh * SD_ + (s0 + w * 16 + lo) * 64 + et * 16 + hi * 4) = pk;
            } else {
                // K: tiled swizzle-image
                int row = w * 16 + lo;
                int sl  = et * 2 + (hi >> 1);
                int b8  = (row * 8 + (sl ^ (row & 7))) * 2 + (hi & 1);
                *(uint2*)(Kg + bh * SD_ + t_ * 4096 + b8 * 4) = pk;
            }
        }
    }
    // V: C[s][e] = X . Wv  -> thread holds s = w*16+hi*4+(0..3), e = nt*16+lo
    // Vt tiled swizzle-image: row = e (d), slots along s
#pragma unroll
    for (int nt = 0; nt < 4; ++nt) {
        int erow = nt * 16 + lo;
        bf16x8 wb0 = *(const bf16x8*)(w_lds[2] + erow * 64 + ((hi ^ (erow & 7)) << 3));
        bf16x8 wb1 = *(const bf16x8*)(w_lds[2] + erow * 64 + (((4 + hi) ^ (erow & 7)) << 3));
        f32x4 acc = {0.f, 0.f, 0.f, 0.f};
        acc = MFMA(xf0, wb0, acc);
        acc = MFMA(xf1, wb1, acc);
        float bvv = bias[(2 * H_ + h) * 64 + nt * 16 + lo];
        acc += bvv;
        uint2 pk;
        pk.x = cvtpk(acc[0], acc[1]);
        pk.y = cvtpk(acc[2], acc[3]);
        int row = nt * 16 + lo;
        int sl  = w * 2 + (hi >> 1);
        int b8  = (row * 8 + (sl ^ (row & 7))) * 2 + (hi & 1);
        *(uint2*)(Vtg + bh * SD_ + t_ * 4096 + b8 * 4) = pk;
    }
}

// ---------------------------------------------------------------------------
// attn: flash attention, swapped QK^T, KVBLK=64, 8 waves x 16 q (QBLK=128)
// global_load_lds double-buffer staging (pre-swizzled global image), 1 barrier/tile
// ---------------------------------------------------------------------------
__global__ __launch_bounds__(512, 4) void attn_kernel(
    const unsigned short* __restrict__ Qg,
    const unsigned short* __restrict__ Kg,
    const unsigned short* __restrict__ Vtg,
    float* __restrict__ outp)
{
    __shared__ unsigned short k_lds[2][64 * 64];   // K image  (8 KiB each)
    __shared__ unsigned short v_lds[2][64 * 64];   // Vt image

    const int blk = blockIdx.x;                 // 1024, XCD-bijective swizzle
    const int bh  = (blk & 7) + ((blk >> 7) << 3);
    const int qt  = (blk >> 3) & 15;
    const int batch = bh >> 4, hd = bh & 15;
    const int tid = threadIdx.x, lane = tid & 63, w = tid >> 6;  // w = 0..7
    const int lo = lane & 15, hi = lane >> 4;
    const int q0 = qt * 128 + w * 16;

    const unsigned short* Qb = Qg + bh * SD_;
    const char* Kt = (const char*)(Kg  + bh * SD_);   // tiled: +t*8192 bytes
    const char* Vt = (const char*)(Vtg + bh * SD_);

    // Q B-frags (scale pre-folded): lane holds Q[q0+lo][hi*8..+8], [32+hi*8..+8]
    bf16x8 qf0 = *(const bf16x8*)(Qb + (q0 + lo) * 64 + hi * 8);
    bf16x8 qf1 = *(const bf16x8*)(Qb + (q0 + lo) * 64 + 32 + hi * 8);

    const int choff = w * 1024 + lane * 16;  // byte offset in tile (this lane's chunk)
    const int ldsw  = w * 512;               // element offset of wave's 1KB LDS chunk

    f32x4 o[4];
#pragma unroll
    for (int dt = 0; dt < 4; ++dt) o[dt] = (f32x4){0.f, 0.f, 0.f, 0.f};
    float m_run = -1e30f, l_run = 0.0f;

    const int swA = (hi ^ (lo & 7)) << 3;
    const int swB = ((4 + hi) ^ (lo & 7)) << 3;
    const int rb  = lo * 64;

    // prologue: stage tile 0 into buf0
    gload16(Kt + choff, &k_lds[0][ldsw]);
    gload16(Vt + choff, &v_lds[0][ldsw]);
    __syncthreads();

#pragma unroll 1
    for (int t = 0; t < 32; ++t) {
        const unsigned short* kl = k_lds[t & 1];
        const unsigned short* vl = v_lds[t & 1];
        if (t + 1 < 32) {   // prefetch next tile into the other buffer
            gload16(Kt + (t + 1) * 8192 + choff, &k_lds[(t + 1) & 1][ldsw]);
            gload16(Vt + (t + 1) * 8192 + choff, &v_lds[(t + 1) & 1][ldsw]);
        }

        // S^T[k][q] = K . Q^T
        f32x4 st[4];
        __builtin_amdgcn_s_setprio(1);
#pragma unroll
        for (int kt = 0; kt < 4; ++kt) {
            bf16x8 ka0 = *(const bf16x8*)(kl + kt * 1024 + rb + swA);
            bf16x8 ka1 = *(const bf16x8*)(kl + kt * 1024 + rb + swB);
            f32x4 acc = {0.f, 0.f, 0.f, 0.f};
            acc = MFMA(ka0, qf0, acc);
            acc = MFMA(ka1, qf1, acc);
            st[kt] = acc;
        }
        __builtin_amdgcn_s_setprio(0);

        // row max (16 local values + cross-group reduce)
        float m0 = fmaxf(fmaxf(st[0][0], st[0][1]), fmaxf(st[0][2], st[0][3]));
        float m1 = fmaxf(fmaxf(st[1][0], st[1][1]), fmaxf(st[1][2], st[1][3]));
        float m2 = fmaxf(fmaxf(st[2][0], st[2][1]), fmaxf(st[2][2], st[2][3]));
        float m3 = fmaxf(fmaxf(st[3][0], st[3][1]), fmaxf(st[3][2], st[3][3]));
        float mx = fmaxf(fmaxf(m0, m1), fmaxf(m2, m3));
        mx = fmaxf(mx, __shfl_xor(mx, 16));
        mx = fmaxf(mx, __shfl_xor(mx, 32));

        // defer-max (T13): only rescale when the max grew by > 8 (exp2 domain)
        if (!__all(mx - m_run <= 8.0f)) {
            float m_new = fmaxf(m_run, mx);
            float alpha = exp2fast(m_run - m_new);
            l_run *= alpha;
#pragma unroll
            for (int dt = 0; dt < 4; ++dt) o[dt] *= alpha;
            m_run = m_new;
        }

        // P = exp2(S - m_run), packed straight to bf16 pairs
        float rs = 0.f;
        unsigned int pk[4][2];
#pragma unroll
        for (int kt = 0; kt < 4; ++kt) {
            float e0 = exp2fast(st[kt][0] - m_run);
            float e1 = exp2fast(st[kt][1] - m_run);
            float e2 = exp2fast(st[kt][2] - m_run);
            float e3 = exp2fast(st[kt][3] - m_run);
            rs += (e0 + e1) + (e2 + e3);
            pk[kt][0] = cvtpk(e0, e1);
            pk[kt][1] = cvtpk(e2, e3);
        }
        rs += __shfl_xor(rs, 16);
        rs += __shfl_xor(rs, 32);
        l_run += rs;

        // P^T C-layout -> B-frags: permlane32_swap + ds_swizzle(xor16) + select
        union Frag { bf16x8 v; unsigned int u[4]; };
        Frag pb0, pb1;
        const bool oddhi = (hi & 1);
#pragma unroll
        for (int c = 0; c < 2; ++c) {
            uint2v r = __builtin_amdgcn_permlane32_swap(pk[0][c], pk[1][c], false, false);
            unsigned int sx = (unsigned int)__builtin_amdgcn_ds_swizzle((int)r.x, 0x401F);
            unsigned int sy = (unsigned int)__builtin_amdgcn_ds_swizzle((int)r.y, 0x401F);
            pb0.u[c]     = oddhi ? sy  : r.x;
            pb0.u[2 + c] = oddhi ? r.y : sx;
            uint2v r2 = __builtin_amdgcn_permlane32_swap(pk[2][c], pk[3][c], false, false);
            unsigned int sx2 = (unsigned int)__builtin_amdgcn_ds_swizzle((int)r2.x, 0x401F);
            unsigned int sy2 = (unsigned int)__builtin_amdgcn_ds_swizzle((int)r2.y, 0x401F);
            pb1.u[c]     = oddhi ? sy2  : r2.x;
            pb1.u[2 + c] = oddhi ? r2.y : sx2;
        }

        // O^T[d][q] += V^T . P^T
        __builtin_amdgcn_s_setprio(1);
#pragma unroll
        for (int dt = 0; dt < 4; ++dt) {
            bf16x8 va0 = *(const bf16x8*)(vl + dt * 1024 + rb + swA);
            bf16x8 va1 = *(const bf16x8*)(vl + dt * 1024 + rb + swB);
            o[dt] = MFMA(va0, pb0.v, o[dt]);
            o[dt] = MFMA(va1, pb1.v, o[dt]);
        }
        __builtin_amdgcn_s_setprio(0);

        __syncthreads();
    }

    const float inv = 1.0f / l_run;
    float* ob = outp + (size_t)(batch * S_ + q0 + lo) * E_ + hd * 64;
#pragma unroll
    for (int dt = 0; dt < 4; ++dt) {
        f32x4 r = o[dt] * inv;
        *(f32x4*)(ob + dt * 16 + hi * 4) = r;     // 16B coalesced store
    }
}

// ---------------------------------------------------------------------------
extern "C" void kernel_launch(void* const* d_in, const int* in_sizes, int n_in,
                              void* d_out, int out_size, void* d_ws, size_t ws_size,
                              hipStream_t stream)
{
    const float* x  = (const float*)d_in[0];
    const float* Wq = (const float*)d_in[1];
    const float* bq = (const float*)d_in[2];
    const float* Wk = (const float*)d_in[3];
    const float* bk = (const float*)d_in[4];
    const float* Wv = (const float*)d_in[5];
    const float* bv = (const float*)d_in[6];

    char* ws = (char*)d_ws;
    unsigned short* wt   = (unsigned short*)ws;                       // 393216 B
    float*          bias = (float*)(ws + 393216);                     // 12288 B
    unsigned short* Qg   = (unsigned short*)(ws + 405504);            // 16 MiB
    unsigned short* Kg   = (unsigned short*)(ws + 405504 + 16777216);
    unsigned short* Vtg  = (unsigned short*)(ws + 405504 + 2 * 16777216);
    float* outp = (float*)d_out;

    hipLaunchKernelGGL(prep_kernel, dim3(48),   dim3(256), 0, stream,
                       Wq, bq, Wk, bk, Wv, bv, wt, bias);
    hipLaunchKernelGGL(proj_kernel, dim3(2048), dim3(256), 0, stream,
                       x, wt, bias, Qg, Kg, Vtg);
    hipLaunchKernelGGL(attn_kernel, dim3(1024), dim3(512), 0, stream,
                       Qg, Kg, Vtg, outp);
}

// Round 5
// 205.541 us; speedup vs baseline: 1.3173x; 1.0415x over previous
//
#include <hip/hip_runtime.h>

#define B_ 4
#define S_ 2048
#define E_ 1024
#define H_ 16
#define D_ 64
#define BH_ (B_*H_)
#define SD_ (S_*D_)

// log2(e)/8 : folds both 1/sqrt(D) and the exp->exp2 conversion into Q
#define QSCALE 0.18033688011112042f

typedef __attribute__((ext_vector_type(4))) float f32x4;
typedef __attribute__((ext_vector_type(8))) short bf16x8;
typedef __attribute__((ext_vector_type(2))) unsigned int uint2v;

#define MFMA(a,b,c) __builtin_amdgcn_mfma_f32_16x16x32_bf16((a),(b),(c),0,0,0)

__device__ __forceinline__ unsigned short f2bf(float f) {
    unsigned int u = __float_as_uint(f);
    unsigned int r = (u + 0x7fffu + ((u >> 16) & 1u)) >> 16;   // RNE
    return (unsigned short)r;
}

// v_cvt_pk_bf16_f32: dst.lo = bf16(a), dst.hi = bf16(b) (RNE)
__device__ __forceinline__ unsigned int cvtpk(float a, float b) {
    unsigned int r;
    asm("v_cvt_pk_bf16_f32 %0, %1, %2" : "=v"(r) : "v"(a), "v"(b));
    return r;
}

// v_exp_f32: r = 2^x (hardware transcendental)
__device__ __forceinline__ float exp2fast(float x) {
    float r;
    asm("v_exp_f32 %0, %1" : "=v"(r) : "v"(x));
    return r;
}

// v_max3_f32 (T17)
__device__ __forceinline__ float max3f(float a, float b, float c) {
    float r;
    asm("v_max3_f32 %0, %1, %2, %3" : "=v"(r) : "v"(a), "v"(b), "v"(c));
    return r;
}

// async global->LDS, 16B per lane; LDS dest = wave-uniform base + lane*16
__device__ __forceinline__ void gload16(const void* g, void* l) {
    __builtin_amdgcn_global_load_lds(
        (const __attribute__((address_space(1))) unsigned int*)g,
        (__attribute__((address_space(3))) unsigned int*)l, 16, 0, 0);
}

// ---------------------------------------------------------------------------
// prep: W[h][d][e] fp32 -> Wt[mat][h][e][d] bf16 (Q pre-scaled), bias fp32
// 192 blocks: (mat, h, d-chunk of 16)
// ---------------------------------------------------------------------------
__global__ __launch_bounds__(256) void prep_kernel(
    const float* __restrict__ Wq, const float* __restrict__ bq,
    const float* __restrict__ Wk, const float* __restrict__ bk,
    const float* __restrict__ Wv, const float* __restrict__ bv,
    unsigned short* __restrict__ wt, float* __restrict__ bias)
{
    const int blk = blockIdx.x;            // 192 = 3 mats * 16 heads * 4 dchunks
    const int mat = blk >> 6, rest = blk & 63;
    const int h = rest >> 2, dc = rest & 3;
    const float* W    = (mat == 0) ? Wq : (mat == 1) ? Wk : Wv;
    const float* bsrc = (mat == 0) ? bq : (mat == 1) ? bk : bv;
    const float scale = (mat == 0) ? QSCALE : 1.0f;
    const int tid = threadIdx.x;
#pragma unroll
    for (int i = 0; i < 4; ++i) {
        int idx = tid + i * 256;           // 0..1023
        int d = dc * 16 + (idx >> 6), e = idx & 63;
        wt[((mat * H_ + h) << 12) + e * 64 + d] = f2bf(W[h * 4096 + d * 64 + e] * scale);
    }
    if (dc == 0 && tid < 64) bias[(mat * H_ + h) * 64 + tid] = bsrc[h * 64 + tid] * scale;
}

// ---------------------------------------------------------------------------
// proj: Q -> [bh][s][d] bf16 (row layout);
//       K,V -> TILED+SWIZZLED [bh][t][4096] bf16 (LDS image for global_load_lds)
// ---------------------------------------------------------------------------
__global__ __launch_bounds__(256) void proj_kernel(
    const float* __restrict__ x,
    const unsigned short* __restrict__ wt,
    const float* __restrict__ bias,
    unsigned short* __restrict__ Qg,
    unsigned short* __restrict__ Kg,
    unsigned short* __restrict__ Vtg)
{
    __shared__ unsigned short x_lds[64 * 64];      // 8 KiB, swizzled 16B slots
    __shared__ unsigned short w_lds[3][64 * 64];   // 24 KiB

    const int blk = blockIdx.x;                    // 2048
    const int bh  = blk >> 5;
    const int t_  = blk & 31;                      // s-tile index
    const int s0  = t_ << 6;
    const int batch = bh >> 4, h = bh & 15;
    const int tid = threadIdx.x, lane = tid & 63, w = tid >> 6;
    const int lo = lane & 15, hi = lane >> 4;

    // stage X tile (64 s-rows x 64 d) fp32->bf16, swizzled
#pragma unroll
    for (int rnd = 0; rnd < 4; ++rnd) {
        int c = tid + rnd * 256;                   // 0..1023 chunks of 4 floats
        int row = c >> 4, sl4 = c & 15;
        float4 xv = *(const float4*)(x + (size_t)(batch * S_ + s0 + row) * E_ + h * 64 + sl4 * 4);
        int off = row * 64 + (((sl4 >> 1) ^ (row & 7)) << 3) + ((sl4 & 1) << 2);
        uint2 pk;
        pk.x = cvtpk(xv.x, xv.y);
        pk.y = cvtpk(xv.z, xv.w);
        *(uint2*)(x_lds + off) = pk;
    }
    // stage Wt (3 x 64e x 64d bf16), swizzled
#pragma unroll
    for (int rnd = 0; rnd < 6; ++rnd) {
        int c = tid + rnd * 256;                   // 0..1535 chunks of 16B
        int mat = c >> 9, cc = c & 511;
        int row = cc >> 3, slot = cc & 7;
        *(uint4*)(w_lds[mat] + row * 64 + ((slot ^ (row & 7)) << 3)) =
            *(const uint4*)(wt + ((mat * H_ + h) << 12) + row * 64 + slot * 8);
    }
    __syncthreads();

    // this wave's s-chunk x fragments (shared by Q/K B-operand and V A-operand)
    const int xrow = w * 16 + lo;
    bf16x8 xf0 = *(const bf16x8*)(x_lds + xrow * 64 + ((hi ^ (xrow & 7)) << 3));
    bf16x8 xf1 = *(const bf16x8*)(x_lds + xrow * 64 + (((4 + hi) ^ (xrow & 7)) << 3));

    // Q, K: C[e][s] = Wt . X^T  -> thread holds e = et*16+hi*4+(0..3), s = w*16+lo
#pragma unroll
    for (int mat = 0; mat < 2; ++mat) {
        const unsigned short* wl = w_lds[mat];
#pragma unroll
        for (int et = 0; et < 4; ++et) {
            int erow = et * 16 + lo;
            bf16x8 wa0 = *(const bf16x8*)(wl + erow * 64 + ((hi ^ (erow & 7)) << 3));
            bf16x8 wa1 = *(const bf16x8*)(wl + erow * 64 + (((4 + hi) ^ (erow & 7)) << 3));
            f32x4 acc = {0.f, 0.f, 0.f, 0.f};
            acc = MFMA(wa0, xf0, acc);
            acc = MFMA(wa1, xf1, acc);
            f32x4 bv = *(const f32x4*)(bias + (mat * H_ + h) * 64 + et * 16 + hi * 4);
            acc += bv;
            uint2 pk;
            pk.x = cvtpk(acc[0], acc[1]);
            pk.y = cvtpk(acc[2], acc[3]);
            if (mat == 0) {
                // Q: plain row layout [s][e]
                *(uint2*)(Qg + bh * SD_ + (s0 + w * 16 + lo) * 64 + et * 16 + hi * 4) = pk;
            } else {
                // K: tiled swizzle-image
                int row = w * 16 + lo;
                int sl  = et * 2 + (hi >> 1);
                int b8  = (row * 8 + (sl ^ (row & 7))) * 2 + (hi & 1);
                *(uint2*)(Kg + bh * SD_ + t_ * 4096 + b8 * 4) = pk;
            }
        }
    }
    // V: C[s][e] = X . Wv  -> thread holds s = w*16+hi*4+(0..3), e = nt*16+lo
    // Vt tiled swizzle-image: row = e (d), slots along s
#pragma unroll
    for (int nt = 0; nt < 4; ++nt) {
        int erow = nt * 16 + lo;
        bf16x8 wb0 = *(const bf16x8*)(w_lds[2] + erow * 64 + ((hi ^ (erow & 7)) << 3));
        bf16x8 wb1 = *(const bf16x8*)(w_lds[2] + erow * 64 + (((4 + hi) ^ (erow & 7)) << 3));
        f32x4 acc = {0.f, 0.f, 0.f, 0.f};
        acc = MFMA(xf0, wb0, acc);
        acc = MFMA(xf1, wb1, acc);
        float bvv = bias[(2 * H_ + h) * 64 + nt * 16 + lo];
        acc += bvv;
        uint2 pk;
        pk.x = cvtpk(acc[0], acc[1]);
        pk.y = cvtpk(acc[2], acc[3]);
        int row = nt * 16 + lo;
        int sl  = w * 2 + (hi >> 1);
        int b8  = (row * 8 + (sl ^ (row & 7))) * 2 + (hi & 1);
        *(uint2*)(Vtg + bh * SD_ + t_ * 4096 + b8 * 4) = pk;
    }
}

// ---------------------------------------------------------------------------
// attn: flash attention, swapped QK^T, KVBLK=64, 8 waves x 16 q (QBLK=128)
// global_load_lds double-buffer; m folded into MFMA C-init; l via ones-row MFMA
// ---------------------------------------------------------------------------
__global__ __launch_bounds__(512, 4) void attn_kernel(
    const unsigned short* __restrict__ Qg,
    const unsigned short* __restrict__ Kg,
    const unsigned short* __restrict__ Vtg,
    float* __restrict__ outp)
{
    __shared__ unsigned short k_lds[2][64 * 64];   // K image  (8 KiB each)
    __shared__ unsigned short v_lds[2][64 * 64];   // Vt image

    const int blk = blockIdx.x;                 // 1024, XCD-bijective swizzle
    const int bh  = (blk & 7) + ((blk >> 7) << 3);
    const int qt  = (blk >> 3) & 15;
    const int batch = bh >> 4, hd = bh & 15;
    const int tid = threadIdx.x, lane = tid & 63, w = tid >> 6;  // w = 0..7
    const int lo = lane & 15, hi = lane >> 4;
    const int q0 = qt * 128 + w * 16;

    const unsigned short* Qb = Qg + bh * SD_;
    const char* Kt = (const char*)(Kg  + bh * SD_);   // tiled: +t*8192 bytes
    const char* Vt = (const char*)(Vtg + bh * SD_);

    // Q B-frags (scale pre-folded): lane holds Q[q0+lo][hi*8..+8], [32+hi*8..+8]
    bf16x8 qf0 = *(const bf16x8*)(Qb + (q0 + lo) * 64 + hi * 8);
    bf16x8 qf1 = *(const bf16x8*)(Qb + (q0 + lo) * 64 + 32 + hi * 8);

    // ones A-fragment (bf16 1.0 = 0x3F80) for the l row-sum MFMA
    bf16x8 onesA;
#pragma unroll
    for (int j = 0; j < 8; ++j) onesA[j] = (short)0x3F80;

    const int choff = w * 1024 + lane * 16;  // byte offset in tile (this lane's chunk)
    const int ldsw  = w * 512;               // element offset of wave's 1KB LDS chunk

    f32x4 o[4];
#pragma unroll
    for (int dt = 0; dt < 4; ++dt) o[dt] = (f32x4){0.f, 0.f, 0.f, 0.f};
    float m_run = 0.0f, l_run = 0.0f;        // m starts at 0 (NOT -inf): defer-max
                                             // keeps P <= 2^8 once m catches up

    const int swA = (hi ^ (lo & 7)) << 3;
    const int swB = ((4 + hi) ^ (lo & 7)) << 3;
    const int rb  = lo * 64;

    // prologue: stage tile 0 into buf0
    gload16(Kt + choff, &k_lds[0][ldsw]);
    gload16(Vt + choff, &v_lds[0][ldsw]);
    __syncthreads();

#pragma unroll 1
    for (int t = 0; t < 32; ++t) {
        const unsigned short* kl = k_lds[t & 1];
        const unsigned short* vl = v_lds[t & 1];
        if (t + 1 < 32) {   // prefetch next tile into the other buffer
            gload16(Kt + (t + 1) * 8192 + choff, &k_lds[(t + 1) & 1][ldsw]);
            gload16(Vt + (t + 1) * 8192 + choff, &v_lds[(t + 1) & 1][ldsw]);
        }

        // S^T[k][q] - m_run = K . Q^T + (-m_run)   (m folded into C-init)
        const f32x4 minit = {-m_run, -m_run, -m_run, -m_run};
        f32x4 st[4];
        __builtin_amdgcn_s_setprio(1);
#pragma unroll
        for (int kt = 0; kt < 4; ++kt) {
            bf16x8 ka0 = *(const bf16x8*)(kl + kt * 1024 + rb + swA);
            bf16x8 ka1 = *(const bf16x8*)(kl + kt * 1024 + rb + swB);
            f32x4 acc = MFMA(ka0, qf0, minit);
            acc = MFMA(ka1, qf1, acc);
            st[kt] = acc;
        }
        __builtin_amdgcn_s_setprio(0);

        // row max of the 16 shifted scores (v_max3 tree) + cross-group reduce
        float a0 = max3f(st[0][0], st[0][1], st[0][2]);
        float a1 = max3f(st[0][3], st[1][0], st[1][1]);
        float a2 = max3f(st[1][2], st[1][3], st[2][0]);
        float a3 = max3f(st[2][1], st[2][2], st[2][3]);
        float a4 = max3f(st[3][0], st[3][1], st[3][2]);
        float mx = max3f(fmaxf(a0, st[3][3]), fmaxf(a1, a2), fmaxf(a3, a4));
        mx = fmaxf(mx, __shfl_xor(mx, 16));
        mx = fmaxf(mx, __shfl_xor(mx, 32));

        // defer-max (T13): rescale only when max grew by > 8 over m_run
        if (!__all(mx <= 8.0f)) {
            float delta = fmaxf(mx, 0.0f);
            float alpha = exp2fast(-delta);
            l_run *= alpha;
#pragma unroll
            for (int dt = 0; dt < 4; ++dt) o[dt] *= alpha;
#pragma unroll
            for (int kt = 0; kt < 4; ++kt)
#pragma unroll
                for (int r = 0; r < 4; ++r) st[kt][r] -= delta;
            m_run += delta;
        }

        // P = exp2(st), packed straight to bf16 pairs (no subtract needed)
        unsigned int pk[4][2];
#pragma unroll
        for (int kt = 0; kt < 4; ++kt) {
            float e0 = exp2fast(st[kt][0]);
            float e1 = exp2fast(st[kt][1]);
            float e2 = exp2fast(st[kt][2]);
            float e3 = exp2fast(st[kt][3]);
            pk[kt][0] = cvtpk(e0, e1);
            pk[kt][1] = cvtpk(e2, e3);
        }

        // P^T C-layout -> B-frags: permlane32_swap + ds_swizzle(xor16) + select
        union Frag { bf16x8 v; unsigned int u[4]; };
        Frag pb0, pb1;
        const bool oddhi = (hi & 1);
#pragma unroll
        for (int c = 0; c < 2; ++c) {
            uint2v r = __builtin_amdgcn_permlane32_swap(pk[0][c], pk[1][c], false, false);
            unsigned int sx = (unsigned int)__builtin_amdgcn_ds_swizzle((int)r.x, 0x401F);
            unsigned int sy = (unsigned int)__builtin_amdgcn_ds_swizzle((int)r.y, 0x401F);
            pb0.u[c]     = oddhi ? sy  : r.x;
            pb0.u[2 + c] = oddhi ? r.y : sx;
            uint2v r2 = __builtin_amdgcn_permlane32_swap(pk[2][c], pk[3][c], false, false);
            unsigned int sx2 = (unsigned int)__builtin_amdgcn_ds_swizzle((int)r2.x, 0x401F);
            unsigned int sy2 = (unsigned int)__builtin_amdgcn_ds_swizzle((int)r2.y, 0x401F);
            pb1.u[c]     = oddhi ? sy2  : r2.x;
            pb1.u[2 + c] = oddhi ? r2.y : sx2;
        }

        // l row-sum via ones-row MFMA + O^T[d][q] += V^T . P^T
        __builtin_amdgcn_s_setprio(1);
        f32x4 lz = {0.f, 0.f, 0.f, 0.f};
        lz = MFMA(onesA, pb0.v, lz);
        lz = MFMA(onesA, pb1.v, lz);
#pragma unroll
        for (int dt = 0; dt < 4; ++dt) {
            bf16x8 va0 = *(const bf16x8*)(vl + dt * 1024 + rb + swA);
            bf16x8 va1 = *(const bf16x8*)(vl + dt * 1024 + rb + swB);
            o[dt] = MFMA(va0, pb0.v, o[dt]);
            o[dt] = MFMA(va1, pb1.v, o[dt]);
        }
        __builtin_amdgcn_s_setprio(0);
        l_run += lz[0];                       // lane holds l for q = lo directly

        __syncthreads();
    }

    const float inv = 1.0f / l_run;
    float* ob = outp + (size_t)(batch * S_ + q0 + lo) * E_ + hd * 64;
#pragma unroll
    for (int dt = 0; dt < 4; ++dt) {
        f32x4 r = o[dt] * inv;
        *(f32x4*)(ob + dt * 16 + hi * 4) = r;     // 16B coalesced store
    }
}

// ---------------------------------------------------------------------------
extern "C" void kernel_launch(void* const* d_in, const int* in_sizes, int n_in,
                              void* d_out, int out_size, void* d_ws, size_t ws_size,
                              hipStream_t stream)
{
    const float* x  = (const float*)d_in[0];
    const float* Wq = (const float*)d_in[1];
    const float* bq = (const float*)d_in[2];
    const float* Wk = (const float*)d_in[3];
    const float* bk = (const float*)d_in[4];
    const float* Wv = (const float*)d_in[5];
    const float* bv = (const float*)d_in[6];

    char* ws = (char*)d_ws;
    unsigned short* wt   = (unsigned short*)ws;                       // 393216 B
    float*          bias = (float*)(ws + 393216);                     // 12288 B
    unsigned short* Qg   = (unsigned short*)(ws + 405504);            // 16 MiB
    unsigned short* Kg   = (unsigned short*)(ws + 405504 + 16777216);
    unsigned short* Vtg  = (unsigned short*)(ws + 405504 + 2 * 16777216);
    float* outp = (float*)d_out;

    hipLaunchKernelGGL(prep_kernel, dim3(192),  dim3(256), 0, stream,
                       Wq, bq, Wk, bk, Wv, bv, wt, bias);
    hipLaunchKernelGGL(proj_kernel, dim3(2048), dim3(256), 0, stream,
                       x, wt, bias, Qg, Kg, Vtg);
    hipLaunchKernelGGL(attn_kernel, dim3(1024), dim3(512), 0, stream,
                       Qg, Kg, Vtg, outp);
}